// Round 2
// baseline (2561.690 us; speedup 1.0000x reference)
//
#include <hip/hip_runtime.h>

#define VV 50257
#define DD 50
#define TT 1024
#define BB 1024

__device__ __forceinline__ float rl(float v, int lane) {
    return __int_as_float(__builtin_amdgcn_readlane(__float_as_int(v), lane));
}
__device__ __forceinline__ float sigmf(float x) { return 1.0f / (1.0f + __expf(-x)); }
__device__ __forceinline__ float tanhf_fast(float x) {
    float e = __expf(-2.0f * fabsf(x));
    return copysignf((1.0f - e) / (1.0f + e), x);
}

// P1[v][j] = b1[0][j] + sum_d emb[v][d] * kx1[d][j]   (one-time, ~0.5 GFLOP)
__global__ void proj_emb(const float* __restrict__ emb, const float* __restrict__ kx1,
                         const float* __restrict__ b1, float* __restrict__ P1) {
    int j = threadIdx.x;             // 0..95
    int v0 = blockIdx.x * 8;
    #pragma unroll 1
    for (int vv = 0; vv < 8; ++vv) {
        int v = v0 + vv;
        if (v >= VV) return;
        float acc = b1[j];
        #pragma unroll
        for (int d = 0; d < DD; ++d)
            acc += emb[v * DD + d] * kx1[d * 96 + j];
        P1[v * 96 + j] = acc;
    }
}

// One wave per batch row; all weights register-resident; no LDS, no barriers.
// Per lane c (0..63):
//   GRU2: owns columns c (z), 64+c (r), 128+c (h) of kx2/kh2 -> computes h2[c].
//   GRU1: acc A = col `lane` of kh1 (z cols 0-31 on lanes 0-31, r cols on 32-63);
//         acc B = h col 64+(lane&31).  New h1 lives in lanes 0-31.
// Broadcasts h1/h2 via v_readlane (SGPR operand feeds FMAs directly).
__global__ __launch_bounds__(256, 1)
void rnn_seq(const int* __restrict__ tokens, const float* __restrict__ P1,
             const float* __restrict__ kh1, const float* __restrict__ b1,
             const float* __restrict__ kx2, const float* __restrict__ kh2,
             const float* __restrict__ b2, const float* __restrict__ wg,
             const float* __restrict__ bg, const float* __restrict__ wd,
             const float* __restrict__ bd, float* __restrict__ out) {
    const int lane = threadIdx.x & 63;
    const int row  = blockIdx.x * 4 + (threadIdx.x >> 6);
    const int l32  = lane & 31;

    // ---- register-resident weights (one-time coalesced loads) ----
    float wh2z[64], wh2r[64], wh2h[64];
    #pragma unroll
    for (int k = 0; k < 64; ++k) {
        wh2z[k] = kh2[k * 192 + lane];
        wh2r[k] = kh2[k * 192 + 64 + lane];
        wh2h[k] = kh2[k * 192 + 128 + lane];
    }
    float wx2z[32], wx2r[32], wx2h[32];
    #pragma unroll
    for (int k = 0; k < 32; ++k) {
        wx2z[k] = kx2[k * 192 + lane];
        wx2r[k] = kx2[k * 192 + 64 + lane];
        wx2h[k] = kx2[k * 192 + 128 + lane];
    }
    float w1a[32], w1b[32];
    #pragma unroll
    for (int k = 0; k < 32; ++k) {
        w1a[k] = kh1[k * 96 + lane];
        w1b[k] = kh1[k * 96 + 64 + l32];
    }
    // biases
    const float bxz = b2[lane],       bxr = b2[64 + lane],  bxh = b2[128 + lane];
    const float bhz = b2[192 + lane], bhr = b2[256 + lane], bhh = b2[320 + lane];
    const float b1a = b1[96 + lane],  b1b = b1[160 + l32];

    const int tbase = row * TT;
    int tok0 = tokens[tbase];
    int tok1 = tokens[tbase + 1];
    int tokc = tokens[tbase + 2];        // token for step t+2 (at t=0)

    // p(0)
    float pz = P1[tok0 * 96 + lane];     // z cols on lanes 0-31, r cols on 32-63
    float ph = P1[tok0 * 96 + 64 + l32]; // h cols

    float h1, h2 = 0.f;
    {   // h1(0): recurrent pre-acts are just biases (h1(-1)=0)
        float tmp = b1a + pz;
        float rsh = __shfl_xor(tmp, 32);
        float z  = sigmf(tmp);
        float r  = sigmf(rsh);
        float hh = tanhf_fast(ph + r * b1b);
        h1 = (1.f - z) * hh;             // correct in lanes 0-31 (only those are read)
    }
    // p(1) in flight
    pz = P1[tok1 * 96 + lane];
    ph = P1[tok1 * 96 + 64 + l32];

    #pragma unroll 1
    for (int t = 0; t < TT; ++t) {
        // merged h1(t) broadcast: kx2 (xt2 for GRU2 step t) + kh1 (hm1 for step t+1)
        float azx = bxz, arx = bxr, ahx = bxh;
        float a1a = b1a, a1b = b1b;
        #pragma unroll
        for (int k = 0; k < 32; ++k) {
            float s = rl(h1, k);
            azx += s * wx2z[k];
            arx += s * wx2r[k];
            ahx += s * wx2h[k];
            a1a += s * w1a[k];
            a1b += s * w1b[k];
        }
        // kh2: h2(t-1) broadcast
        float azh = bhz, arh = bhr, ahh = bhh;
        #pragma unroll
        for (int k = 0; k < 64; ++k) {
            float s = rl(h2, k);
            azh += s * wh2z[k];
            arh += s * wh2r[k];
            ahh += s * wh2h[k];
        }
        // GRU2 gates -> h2(t)   (reset applied after recurrent matmul)
        {
            float z  = sigmf(azx + azh);
            float r  = sigmf(arx + arh);
            float hh = tanhf_fast(ahx + r * ahh);
            h2 = z * h2 + (1.f - z) * hh;
        }
        // GRU1 gates -> h1(t+1)  (pz/ph = p(t+1), loaded last iter)
        {
            float tmp = a1a + pz;
            float rsh = __shfl_xor(tmp, 32);
            float z  = sigmf(tmp);
            float r  = sigmf(rsh);
            float hh = tanhf_fast(ph + r * a1b);
            h1 = z * h1 + (1.f - z) * hh;
        }
        // prefetch p(t+2); token for t+3
        pz = P1[tokc * 96 + lane];
        ph = P1[tokc * 96 + 64 + l32];
        int tn = t + 3; if (tn > TT - 1) tn = TT - 1;
        tokc = tokens[tbase + tn];
    }

    // ---- tail: GLU + dense (once per row) ----
    float a0 = bg[lane], a1 = bg[64 + lane], a2 = bg[128 + lane], a3 = bg[192 + lane];
    #pragma unroll 4
    for (int k = 0; k < 64; ++k) {
        float s = rl(h2, k);
        const float* wr = wg + k * 256;
        a0 += s * wr[lane];
        a1 += s * wr[64 + lane];
        a2 += s * wr[128 + lane];
        a3 += s * wr[192 + lane];
    }
    float x0 = a0 * sigmf(a2);
    float x1 = a1 * sigmf(a3);
    float s = x0 * wd[lane] + x1 * wd[64 + lane];
    s += __shfl_xor(s, 32); s += __shfl_xor(s, 16); s += __shfl_xor(s, 8);
    s += __shfl_xor(s, 4);  s += __shfl_xor(s, 2);  s += __shfl_xor(s, 1);
    if (lane == 0) out[row] = sigmf(s + bd[0]);
}

extern "C" void kernel_launch(void* const* d_in, const int* in_sizes, int n_in,
                              void* d_out, int out_size, void* d_ws, size_t ws_size,
                              hipStream_t stream) {
    const int*   tokens = (const int*)d_in[0];
    const float* emb = (const float*)d_in[1];
    const float* kx1 = (const float*)d_in[2];
    const float* kh1 = (const float*)d_in[3];
    const float* b1  = (const float*)d_in[4];
    const float* kx2 = (const float*)d_in[5];
    const float* kh2 = (const float*)d_in[6];
    const float* b2  = (const float*)d_in[7];
    const float* wg  = (const float*)d_in[8];
    const float* bg  = (const float*)d_in[9];
    const float* wd  = (const float*)d_in[10];
    const float* bd  = (const float*)d_in[11];
    float* out = (float*)d_out;
    float* P1  = (float*)d_ws;   // 50257*96*4 = 19.3 MB of workspace

    proj_emb<<<(VV + 7) / 8, 96, 0, stream>>>(emb, kx1, b1, P1);
    rnn_seq<<<BB / 4, 256, 0, stream>>>(tokens, P1, kh1, b1, kx2, kh2, b2,
                                        wg, bg, wd, bd, out);
}

// Round 3
// 2172.171 us; speedup vs baseline: 1.1793x; 1.1793x over previous
//
#include <hip/hip_runtime.h>

#define VV 50257
#define DD 50
#define TT 1024
#define BB 1024

__device__ __forceinline__ float rl(float v, int lane) {
    return __int_as_float(__builtin_amdgcn_readlane(__float_as_int(v), lane));
}
__device__ __forceinline__ float sigmf(float x) { return 1.0f / (1.0f + __expf(-x)); }
__device__ __forceinline__ float tanhf_fast(float x) {
    float e = __expf(-2.0f * fabsf(x));
    return copysignf((1.0f - e) / (1.0f + e), x);
}

// P1[v][j] = b1[0][j] + sum_d emb[v][d] * kx1[d][j]   (one-time, ~0.5 GFLOP)
__global__ void proj_emb(const float* __restrict__ emb, const float* __restrict__ kx1,
                         const float* __restrict__ b1, float* __restrict__ P1) {
    int j = threadIdx.x;             // 0..95
    int v0 = blockIdx.x * 8;
    #pragma unroll 1
    for (int vv = 0; vv < 8; ++vv) {
        int v = v0 + vv;
        if (v >= VV) return;
        float acc = b1[j];
        #pragma unroll
        for (int d = 0; d < DD; ++d)
            acc += emb[v * DD + d] * kx1[d * 96 + j];
        P1[v * 96 + j] = acc;
    }
}

// Block = 2 waves = 1 batch row, 1024 blocks.
// Wave A (wv=0): kh2 in W[] (192 regs), h2 state per-lane, GRU2 gates.
// Wave B (wv=1): kx2+kh1 in W[] (160 regs used), h1 state (lanes 0-31),
//                GRU1 gates, P1 prefetch; ships xt2 via one float4 LDS slot.
// ONE barrier per iter; slot ping-pong on t&1 replaces the second barrier.
// W[] is a single overlaid array so A's and B's weights share one register frame.
__global__ __launch_bounds__(128, 2)
void rnn_seq(const int* __restrict__ tokens, const float* __restrict__ P1,
             const float* __restrict__ kh1, const float* __restrict__ b1,
             const float* __restrict__ kx2, const float* __restrict__ kh2,
             const float* __restrict__ b2, const float* __restrict__ wg,
             const float* __restrict__ bg, const float* __restrict__ wd,
             const float* __restrict__ bd, float* __restrict__ out) {
    const int lane = threadIdx.x & 63;
    const int wv   = threadIdx.x >> 6;
    const int row  = blockIdx.x;
    const int l32  = lane & 31;

    __shared__ float4 slot[2][64];

    float W[192];
    float bias0, bias1, bias2, bias3 = 0.f, bias4 = 0.f;

    if (wv == 0) {
        #pragma unroll
        for (int k = 0; k < 64; ++k) {
            W[3 * k]     = kh2[k * 192 + lane];
            W[3 * k + 1] = kh2[k * 192 + 64 + lane];
            W[3 * k + 2] = kh2[k * 192 + 128 + lane];
        }
        bias0 = b2[192 + lane];          // recurrent biases b2[1]
        bias1 = b2[256 + lane];
        bias2 = b2[320 + lane];
    } else {
        #pragma unroll
        for (int k = 0; k < 32; ++k) {
            W[5 * k]     = kx2[k * 192 + lane];
            W[5 * k + 1] = kx2[k * 192 + 64 + lane];
            W[5 * k + 2] = kx2[k * 192 + 128 + lane];
            W[5 * k + 3] = kh1[k * 96 + lane];          // z|r cols
            W[5 * k + 4] = kh1[k * 96 + 64 + l32];      // h cols
        }
        bias0 = b2[lane];                // input biases b2[0]
        bias1 = b2[64 + lane];
        bias2 = b2[128 + lane];
        bias3 = b1[96 + lane];           // GRU1 recurrent biases b1[1]
        bias4 = b1[96 + 64 + l32];
    }

    float h = 0.f;           // wave A: h2[lane]; wave B: h1[lane] (lanes 0-31 valid)
    float pz = 0.f, ph = 0.f;
    int tokc = 0;
    const int tbase = row * TT;

    if (wv == 1) {
        int tok0 = tokens[tbase];
        int tok1 = tokens[tbase + 1];
        tokc = tokens[tbase + 2];
        // h1(0): recurrent pre-acts are biases only (h1(-1)=0)
        float pz0 = P1[tok0 * 96 + lane];
        float ph0 = P1[tok0 * 96 + 64 + l32];
        float tmp = bias3 + pz0;
        float rsh = __shfl_xor(tmp, 32);
        float z  = sigmf(tmp);
        float r  = sigmf(rsh);
        float hh = tanhf_fast(ph0 + r * bias4);
        h = (1.f - z) * hh;              // valid in lanes 0-31
        // p(1) in flight for iter 0's gate phase
        pz = P1[tok1 * 96 + lane];
        ph = P1[tok1 * 96 + 64 + l32];
    }
    __syncthreads();

    #pragma unroll 1
    for (int t = 0; t < TT; ++t) {
        float a0, a1, a2, a3 = 0.f, a4 = 0.f;
        if (wv == 0) {
            // hm2 = h2(t-1) @ kh2 + b2[1]
            a0 = bias0; a1 = bias1; a2 = bias2;
            #pragma unroll
            for (int k = 0; k < 64; ++k) {
                float s = rl(h, k);
                a0 += s * W[3 * k];
                a1 += s * W[3 * k + 1];
                a2 += s * W[3 * k + 2];
            }
        } else {
            // xt2 = h1(t) @ kx2 + b2[0];  hm1 = h1(t) @ kh1 + b1[1]
            a0 = bias0; a1 = bias1; a2 = bias2; a3 = bias3; a4 = bias4;
            #pragma unroll
            for (int k = 0; k < 32; ++k) {
                float s = rl(h, k);
                a0 += s * W[5 * k];
                a1 += s * W[5 * k + 1];
                a2 += s * W[5 * k + 2];
                a3 += s * W[5 * k + 3];
                a4 += s * W[5 * k + 4];
            }
            slot[t & 1][lane] = make_float4(a0, a1, a2, 0.f);
        }
        __syncthreads();
        if (wv == 0) {
            // GRU2 gates -> h2(t)   (reset applied after recurrent matmul)
            float4 p = slot[t & 1][lane];
            float z  = sigmf(p.x + a0);
            float r  = sigmf(p.y + a1);
            float hh = tanhf_fast(p.z + r * a2);
            h = z * h + (1.f - z) * hh;
        } else {
            // GRU1 gates -> h1(t+1)  (pz/ph = p(t+1))
            float tmp = a3 + pz;
            float rsh = __shfl_xor(tmp, 32);
            float z  = sigmf(tmp);
            float r  = sigmf(rsh);
            float hh = tanhf_fast(ph + r * a4);
            h = z * h + (1.f - z) * hh;
            // prefetch p(t+2); token for t+3
            pz = P1[tokc * 96 + lane];
            ph = P1[tokc * 96 + 64 + l32];
            int tn = t + 3; if (tn > TT - 1) tn = TT - 1;
            tokc = tokens[tbase + tn];
        }
    }

    // ---- tail: GLU + dense, wave A only (h = h2(T-1); no barriers here) ----
    if (wv == 0) {
        float g0 = bg[lane], g1 = bg[64 + lane], g2 = bg[128 + lane], g3 = bg[192 + lane];
        #pragma unroll 4
        for (int k = 0; k < 64; ++k) {
            float s = rl(h, k);
            const float* wr = wg + k * 256;
            g0 += s * wr[lane];
            g1 += s * wr[64 + lane];
            g2 += s * wr[128 + lane];
            g3 += s * wr[192 + lane];
        }
        float x0 = g0 * sigmf(g2);
        float x1 = g1 * sigmf(g3);
        float s = x0 * wd[lane] + x1 * wd[64 + lane];
        s += __shfl_xor(s, 32); s += __shfl_xor(s, 16); s += __shfl_xor(s, 8);
        s += __shfl_xor(s, 4);  s += __shfl_xor(s, 2);  s += __shfl_xor(s, 1);
        if (lane == 0) out[row] = sigmf(s + bd[0]);
    }
}

extern "C" void kernel_launch(void* const* d_in, const int* in_sizes, int n_in,
                              void* d_out, int out_size, void* d_ws, size_t ws_size,
                              hipStream_t stream) {
    const int*   tokens = (const int*)d_in[0];
    const float* emb = (const float*)d_in[1];
    const float* kx1 = (const float*)d_in[2];
    const float* kh1 = (const float*)d_in[3];
    const float* b1  = (const float*)d_in[4];
    const float* kx2 = (const float*)d_in[5];
    const float* kh2 = (const float*)d_in[6];
    const float* b2  = (const float*)d_in[7];
    const float* wg  = (const float*)d_in[8];
    const float* bg  = (const float*)d_in[9];
    const float* wd  = (const float*)d_in[10];
    const float* bd  = (const float*)d_in[11];
    float* out = (float*)d_out;
    float* P1  = (float*)d_ws;   // 50257*96*4 = 19.3 MB of workspace

    proj_emb<<<(VV + 7) / 8, 96, 0, stream>>>(emb, kx1, b1, P1);
    rnn_seq<<<BB, 128, 0, stream>>>(tokens, P1, kh1, b1, kx2, kh2, b2,
                                    wg, bg, wd, bd, out);
}